// Round 12
// baseline (34.994 us; speedup 1.0000x reference)
//
#include <hip/hip_runtime.h>
#include <stdint.h>

#define BINS    64
#define SBINS   256               // sub-bins: 4 per bin (h = 1/4 bin)
#define CSTR    65                // dwords per u8-count column; gcd(65,32)=1
#define THREADS 128
#define CHUNKS  64                // blocks per channel-image
#define NPIX    (512*512)
#define PPB     (NPIX / CHUNKS)   // 4096 px per block -> 32 px/thread (u8 max 32 < 255)
#define ITERS   (PPB / 4 / THREADS)   // 8
#define NCH     12                // 4*3 channel-images per input
#define NIMG    (2 * NCH)         // 24

__global__ __launch_bounds__(THREADS) void hist_kernel(
    const float* __restrict__ pred, const float* __restrict__ target,
    uint32_t* __restrict__ cnt /* [NIMG][SBINS] */)
{
    __shared__ uint32_t lh[THREADS * CSTR];   // 33280 B
    __shared__ uint32_t red[2 * THREADS];     // 1 KB
    const int tid = threadIdx.x;

    uint32_t* col = &lh[tid * CSTR];
    #pragma unroll
    for (int i = 0; i < CSTR; ++i) col[i] = 0u;
    __syncthreads();

    const int chunk = blockIdx.x;
    const int ch    = blockIdx.y;
    const int z     = blockIdx.z;
    const float* src = (z == 0 ? pred : target)
                     + (size_t)ch * NPIX + (size_t)chunk * PPB;
    const float4* src4 = (const float4*)src;

    float4 v = src4[tid];
    #pragma unroll
    for (int k = 0; k < ITERS; ++k) {
        float4 vn = (k + 1 < ITERS) ? src4[(size_t)(k + 1) * THREADS + tid]
                                    : make_float4(0.f, 0.f, 0.f, 0.f);
        float xv[4] = {v.x, v.y, v.z, v.w};
        #pragma unroll
        for (int e = 0; e < 4; ++e) {
            uint32_t kq = (uint32_t)(int)(xv[e] * 256.0f);   // sub-bin 0..255
            col[kq >> 2] += 1u << ((kq & 3u) << 3);          // u8-lane count
        }
        v = vn;
    }
    __syncthreads();

    // SIMD fold: thread t sums dword d = t&63 over 64 columns (half g = t>>6)
    // in packed u16 lanes. lo: sub-bins {4d, 4d+2}; hi: {4d+1, 4d+3}.
    const int d = tid & 63;
    const int g = tid >> 6;
    uint32_t lo = 0u, hi = 0u;
    #pragma unroll 8
    for (int c = 0; c < 64; ++c) {
        uint32_t x = lh[(g * 64 + c) * CSTR + d];
        lo += x & 0x00FF00FFu;
        hi += (x >> 8) & 0x00FF00FFu;
    }
    red[tid] = lo;
    red[THREADS + tid] = hi;
    __syncthreads();

    if (tid < 64) {
        uint32_t tlo = red[tid] + red[tid + 64];
        uint32_t thi = red[THREADS + tid] + red[THREADS + tid + 64];
        uint32_t* cp = cnt + ((size_t)z * NCH + ch) * SBINS + 4 * tid;
        atomicAdd(cp + 0, tlo & 0xFFFFu);   // native u32 atomic, exact
        atomicAdd(cp + 1, thi & 0xFFFFu);
        atomicAdd(cp + 2, tlo >> 16);
        atomicAdd(cp + 3, thi >> 16);
    }
}

// Single block: convert counts, 36-tap Gaussian conv per image, CDF, loss.
__global__ __launch_bounds__(256) void finalize_kernel(
    const uint32_t* __restrict__ cnt, float* __restrict__ out)
{
    __shared__ float scnt[NIMG][SBINS];   // 24 KB
    __shared__ float chist[NIMG][BINS];   // 6 KB
    __shared__ float wsum[4];
    const int tid = threadIdx.x;

    for (int i = tid; i < NIMG * SBINS; i += 256)
        ((float*)scnt)[i] = (float)cnt[i];
    __syncthreads();

    // hist[ci][b] = sum_u K(u) * cnt[ci][4b+u], K(u) = exp(-(((u-1.5)/4)^2)/2)
    for (int o = tid; o < NIMG * BINS; o += 256) {
        int ci = o >> 6, b = o & 63;
        float h = 0.0f;
        #pragma unroll
        for (int u = -16; u <= 19; ++u) {
            int idx = 4 * b + u;
            if (idx >= 0 && idx < SBINS) {
                float t = (u - 1.5f) * 0.25f;
                h += __expf(-0.5f * t * t) * scnt[ci][idx];
            }
        }
        chist[ci][b] = h;
    }
    __syncthreads();

    const int lane = tid & 63;          // lane == bin
    const int w    = tid >> 6;          // wave id 0..3, handles 3 channels
    float acc = 0.0f;
    for (int c = w * 3; c < w * 3 + 3; ++c) {
        float cp = chist[c][lane];
        float ct = chist[NCH + c][lane];
        #pragma unroll
        for (int off = 1; off < 64; off <<= 1) {
            float a = __shfl_up(cp, off, 64);
            float b2 = __shfl_up(ct, off, 64);
            if (lane >= off) { cp += a; ct += b2; }
        }
        float sp = __shfl(cp, 63, 64);
        float st = __shfl(ct, 63, 64);
        float diff = fabsf(cp / (sp + 1e-8f) - ct / (st + 1e-8f));
        #pragma unroll
        for (int off = 32; off; off >>= 1)
            diff += __shfl_xor(diff, off, 64);
        acc += diff;
    }
    if (lane == 0) wsum[w] = acc;
    __syncthreads();
    if (tid == 0)
        out[0] = (wsum[0] + wsum[1] + wsum[2] + wsum[3]) / (float)(NCH * BINS);
}

extern "C" void kernel_launch(void* const* d_in, const int* in_sizes, int n_in,
                              void* d_out, int out_size, void* d_ws, size_t ws_size,
                              hipStream_t stream)
{
    const float* pred   = (const float*)d_in[0];
    const float* target = (const float*)d_in[1];
    uint32_t* cnt = (uint32_t*)d_ws;   // 24*256 u32 = 24 KB

    hipMemsetAsync(cnt, 0, NIMG * SBINS * sizeof(uint32_t), stream);
    hist_kernel<<<dim3(CHUNKS, NCH, 2), THREADS, 0, stream>>>(pred, target, cnt);
    finalize_kernel<<<1, 256, 0, stream>>>(cnt, (float*)d_out);
}

// Round 13
// 18.521 us; speedup vs baseline: 1.8895x; 1.8895x over previous
//
#include <hip/hip_runtime.h>
#include <stdint.h>

#define BINS    64
#define SBINS   256               // sub-bins: 4 per bin (h = 1/4 bin)
#define CSTR    65                // dwords per u8-count column; gcd(65,32)=1
#define THREADS 128
#define CHUNKS  32                // blocks per channel-image
#define NPIX    (512*512)
#define PPB     (NPIX / CHUNKS)   // 8192 px per block -> 64 px/thread (u8 max 64 < 255)
#define ITERS   (PPB / 4 / THREADS)   // 16
#define NCH     12                // 4*3 channel-images per input
#define NIMG    (2 * NCH)         // 24

__global__ __launch_bounds__(THREADS) void hist_kernel(
    const float* __restrict__ pred, const float* __restrict__ target,
    uint32_t* __restrict__ part /* [NIMG][CHUNKS][SBINS] */)
{
    __shared__ uint32_t lh[THREADS * CSTR];   // 33280 B
    __shared__ uint32_t red[2 * THREADS];     // 1 KB
    const int tid = threadIdx.x;

    uint32_t* col = &lh[tid * CSTR];
    #pragma unroll
    for (int i = 0; i < CSTR; ++i) col[i] = 0u;
    __syncthreads();

    const int chunk = blockIdx.x;
    const int ch    = blockIdx.y;
    const int z     = blockIdx.z;
    const float* src = (z == 0 ? pred : target)
                     + (size_t)ch * NPIX + (size_t)chunk * PPB;
    const float4* src4 = (const float4*)src;

    float4 v = src4[tid];
    #pragma unroll
    for (int k = 0; k < ITERS; ++k) {
        float4 vn = (k + 1 < ITERS) ? src4[(size_t)(k + 1) * THREADS + tid]
                                    : make_float4(0.f, 0.f, 0.f, 0.f);
        float xv[4] = {v.x, v.y, v.z, v.w};
        #pragma unroll
        for (int e = 0; e < 4; ++e) {
            uint32_t kq = (uint32_t)(int)(xv[e] * 256.0f);   // sub-bin 0..255
            col[kq >> 2] += 1u << ((kq & 3u) << 3);          // u8-lane count
        }
        v = vn;
    }
    __syncthreads();

    // SIMD fold: thread t sums dword d = t&63 over 64 columns (half g = t>>6)
    // in packed u16 lanes. lo: sub-bins {4d, 4d+2}; hi: {4d+1, 4d+3}.
    const int d = tid & 63;
    const int g = tid >> 6;
    uint32_t lo = 0u, hi = 0u;
    #pragma unroll 8
    for (int c = 0; c < 64; ++c) {
        uint32_t x = lh[(g * 64 + c) * CSTR + d];
        lo += x & 0x00FF00FFu;
        hi += (x >> 8) & 0x00FF00FFu;
    }
    red[tid] = lo;
    red[THREADS + tid] = hi;
    __syncthreads();

    if (tid < 64) {
        uint32_t tlo = red[tid] + red[tid + 64];
        uint32_t thi = red[THREADS + tid] + red[THREADS + tid + 64];
        uint4 o;
        o.x = tlo & 0xFFFFu;        // sub-bin 4d
        o.y = thi & 0xFFFFu;        // sub-bin 4d+1
        o.z = tlo >> 16;            // sub-bin 4d+2
        o.w = thi >> 16;            // sub-bin 4d+3
        uint4* pp = (uint4*)(part + (((size_t)z * NCH + ch) * CHUNKS + chunk) * SBINS);
        pp[tid] = o;                // coalesced 16B/lane store
    }
}

// One block per channel-image: fold chunk partials, then 36-tap Gaussian conv.
__global__ __launch_bounds__(SBINS) void reduce_conv_kernel(
    const uint32_t* __restrict__ part, float* __restrict__ chist /* [NIMG][BINS] */)
{
    __shared__ float cnt[SBINS];
    const int ci = blockIdx.x;
    const int s  = threadIdx.x;
    uint32_t tot = 0u;
    #pragma unroll 8
    for (int i = 0; i < CHUNKS; ++i)
        tot += part[((size_t)ci * CHUNKS + i) * SBINS + s];
    cnt[s] = (float)tot;
    __syncthreads();

    if (s < BINS) {
        // hist_b = sum_u K(u) * cnt[4b+u], K(u) = exp(-(((u-1.5)/4)^2)/2)
        float h = 0.0f;
        #pragma unroll
        for (int u = -16; u <= 19; ++u) {
            int idx = 4 * s + u;
            if (idx >= 0 && idx < SBINS) {
                float t = (u - 1.5f) * 0.25f;
                h += __expf(-0.5f * t * t) * cnt[idx];
            }
        }
        chist[ci * BINS + s] = h;
    }
}

__global__ __launch_bounds__(256) void finalize_kernel(
    const float* __restrict__ chist, float* __restrict__ out)
{
    __shared__ float wsum[4];
    const int tid  = threadIdx.x;
    const int lane = tid & 63;          // lane == bin
    const int w    = tid >> 6;          // wave id 0..3, handles 3 channels
    float acc = 0.0f;
    for (int c = w * 3; c < w * 3 + 3; ++c) {
        float cp = chist[c * BINS + lane];
        float ct = chist[(NCH + c) * BINS + lane];
        #pragma unroll
        for (int off = 1; off < 64; off <<= 1) {
            float a = __shfl_up(cp, off, 64);
            float b = __shfl_up(ct, off, 64);
            if (lane >= off) { cp += a; ct += b; }
        }
        float sp = __shfl(cp, 63, 64);
        float st = __shfl(ct, 63, 64);
        float diff = fabsf(cp / (sp + 1e-8f) - ct / (st + 1e-8f));
        #pragma unroll
        for (int off = 32; off; off >>= 1)
            diff += __shfl_xor(diff, off, 64);
        acc += diff;
    }
    if (lane == 0) wsum[w] = acc;
    __syncthreads();
    if (tid == 0)
        out[0] = (wsum[0] + wsum[1] + wsum[2] + wsum[3]) / (float)(NCH * BINS);
}

extern "C" void kernel_launch(void* const* d_in, const int* in_sizes, int n_in,
                              void* d_out, int out_size, void* d_ws, size_t ws_size,
                              hipStream_t stream)
{
    const float* pred   = (const float*)d_in[0];
    const float* target = (const float*)d_in[1];
    uint32_t* part  = (uint32_t*)d_ws;                    // 24*32*256 u32 = 786 KB
    float*    chist = (float*)(part + (size_t)NIMG * CHUNKS * SBINS); // 24*64 f32

    hist_kernel<<<dim3(CHUNKS, NCH, 2), THREADS, 0, stream>>>(pred, target, part);
    reduce_conv_kernel<<<NIMG, SBINS, 0, stream>>>(part, chist);
    finalize_kernel<<<1, 256, 0, stream>>>(chist, (float*)d_out);
}